// Round 8
// baseline (50.697 us; speedup 1.0000x reference)
//
#include <hip/hip_runtime.h>

// AliasFreeActivation, round 8: persistent 2-unit blocks + cross-unit prefetch,
// barrier-reduced packed-fp32 pipeline.
// x (2,256,84,84) f32 -> up x4 (24t) -> lrelu -> down x2 (12t) -> crop 10
// -> out (2,256,148,148) f32.
//
// Block (b, y): planes pz0=2y, pz0+1; processes band b then band b+5
// (band 9: i0=132, overlaps band 8; duplicate stores bitwise-identical).
// Per band: out rows i0..i0+15; z rows ZR0=2*i0+15 (≡3 mod 4), 42 steps;
// z cols 15..320 (306 local); input rows IR0=i0/2+1..+15 — all in-bounds.
// Sequence: P1L(A) P1S(A) bar P2(A) bar P1L(B) P3(A) bar P1S(B) bar P2(B)
// bar P3(B)  — P1 global loads of B hide under P3(A).
// P2: thread per column-pair, all math float2 -> v_pk_fma_f32; colv/tv are
// thread-private LDS columns so no internal barrier (clamped threads don't
// write). tv aliases uph (barriers order the phases).

typedef float v2 __attribute__((ext_vector_type(2)));

constexpr int IN_HW  = 84;
constexpr int OUT_HW = 148;
constexpr int STR    = 312;               // row stride (dwords)
constexpr int NROWS  = 16;                // out rows per band
constexpr int NZR    = 42;                // z rows per band
constexpr int NIR    = 16;                // uph rows per band
constexpr int PLANE_DW = NIR * STR + 4;   // 4996 dw (pad for P3 b128 tail)
constexpr int NTASK  = 2 * NIR * 39;      // 1248 P1 tasks (both planes)
constexpr float SLOPE = 0.2f;

__device__ __forceinline__ float rfl(float v) {
    return __uint_as_float(__builtin_amdgcn_readfirstlane(__float_as_uint(v)));
}

struct P1Regs { float w[4][8]; };

__device__ __forceinline__ void p1_load(P1Regs& R, const float* __restrict__ x,
                                        int pz0, int IR0, int tid)
{
#pragma unroll
    for (int k = 0; k < 4; ++k) {
        int e = tid + 320 * k;
        if (e < NTASK) {
            int pl = e >= NTASK / 2;
            int e2 = e - pl * (NTASK / 2);
            int r = e2 / 39, g = e2 - 39 * r;
            const float* xr = x + (size_t)(pz0 + pl) * (IN_HW * IN_HW)
                            + (IR0 + r) * IN_HW + 2 * g;
            float2 p0 = *(const float2*)(xr);
            float2 p1 = *(const float2*)(xr + 2);
            float2 p2 = *(const float2*)(xr + 4);
            float2 p3 = *(const float2*)(xr + 6);
            float2 p4 = *(const float2*)(xr + ((g == 38) ? 6 : 8)); // avoid OOB
            R.w[k][0] = p0.y; R.w[k][1] = p1.x; R.w[k][2] = p1.y; R.w[k][3] = p2.x;
            R.w[k][4] = p2.y; R.w[k][5] = p3.x; R.w[k][6] = p3.y; R.w[k][7] = p4.x;
        }
    }
}

__device__ __forceinline__ void p1_store(const P1Regs& R, float* __restrict__ sbuf,
                                         const float* fu, int tid)
{
#pragma unroll
    for (int k = 0; k < 4; ++k) {
        int e = tid + 320 * k;
        if (e < NTASK) {
            int pl = e >= NTASK / 2;
            int e2 = e - pl * (NTASK / 2);
            int r = e2 / 39, g = e2 - 39 * r;
            float w0 = R.w[k][0], w1 = R.w[k][1], w2 = R.w[k][2], w3 = R.w[k][3],
                  w4 = R.w[k][4], w5 = R.w[k][5], w6 = R.w[k][6], w7 = R.w[k][7];
            float4 a, b;
            a.x = fu[1]*w5+fu[5]*w4+fu[9]*w3 +fu[13]*w2+fu[17]*w1+fu[21]*w0;
            a.y = fu[2]*w5+fu[6]*w4+fu[10]*w3+fu[14]*w2+fu[18]*w1+fu[22]*w0;
            a.z = fu[3]*w5+fu[7]*w4+fu[11]*w3+fu[15]*w2+fu[19]*w1+fu[23]*w0;
            a.w = fu[0]*w6+fu[4]*w5+fu[8]*w4 +fu[12]*w3+fu[16]*w2+fu[20]*w1;
            b.x = fu[1]*w6+fu[5]*w5+fu[9]*w4 +fu[13]*w3+fu[17]*w2+fu[21]*w1;
            b.y = fu[2]*w6+fu[6]*w5+fu[10]*w4+fu[14]*w3+fu[18]*w2+fu[22]*w1;
            b.z = fu[3]*w6+fu[7]*w5+fu[11]*w4+fu[15]*w3+fu[19]*w2+fu[23]*w1;
            b.w = fu[0]*w7+fu[4]*w6+fu[8]*w5 +fu[12]*w4+fu[16]*w3+fu[20]*w2;
            float* dst = sbuf + pl * PLANE_DW + r * STR + 8 * g;
            *(float4*)(dst)     = a;
            *(float4*)(dst + 4) = b;
        }
    }
}

__device__ __forceinline__ void p2_col(float* __restrict__ s_pl, int lt,
                                       const float* fu, const float* fd)
{
    const int pc = lt < 153 ? lt : 152;          // clamp (no write if clamped)
    const float* up = s_pl + 2 * pc;
    v2 colv[NIR];
#pragma unroll
    for (int r = 0; r < NIR; ++r) colv[r] = *(const v2*)&up[r * STR];
    v2 acc[NROWS];
#pragma unroll
    for (int i = 0; i < NROWS; ++i) acc[i] = (v2)(0.0f);
#pragma unroll
    for (int s = 0; s < NZR; ++s) {
        const int n  = (s + 1) >> 2;
        const int ph = (s + 1) & 3;
        v2 z = colv[n+5] * fu[ph];
        z += colv[n+4] * fu[ph+4];
        z += colv[n+3] * fu[ph+8];
        z += colv[n+2] * fu[ph+12];
        z += colv[n+1] * fu[ph+16];
        z += colv[n]   * fu[ph+20];
        z = __builtin_elementwise_max(z, z * SLOPE);   // lrelu
        const int m = s >> 1;
#pragma unroll
        for (int k = 0; k < 6; ++k) {                  // static after unroll
            const int li = m - k;
            if (li >= 0 && li < NROWS)
                acc[li] += z * fd[(s & 1) ? (10 - 2*k) : (11 - 2*k)];
        }
    }
    // tv write: same addresses this thread just read -> thread-local, no barrier.
    if (lt < 153) {
        float* tvc = s_pl + 2 * pc;
#pragma unroll
        for (int i = 0; i < NROWS; ++i)
            *(v2*)&tvc[i * STR] = acc[i];
    }
}

__device__ __forceinline__ void p3_store(const float* __restrict__ s_pl,
                                         float* __restrict__ o, int i0, int lt,
                                         const float* fd)
{
    for (int e = lt; e < NROWS * 19; e += 160) {
        int i = e / 19, g8 = e - i * 19;
        float W[28];
#pragma unroll
        for (int k = 0; k < 7; ++k) {
            float4 v = *(const float4*)(s_pl + i * STR + 16 * g8 + 4 * k);
            W[4*k+0]=v.x; W[4*k+1]=v.y; W[4*k+2]=v.z; W[4*k+3]=v.w;
        }
        float ov[8];
#pragma unroll
        for (int m = 0; m < 8; ++m) {
            float s = 0.0f;
#pragma unroll
            for (int u = 0; u < 12; ++u) s += fd[u] * W[2*m + 11 - u];
            ov[m] = s;
        }
        float* orow = o + (size_t)(i0 + i) * OUT_HW + 8 * g8;
        *(float4*)(orow) = make_float4(ov[0], ov[1], ov[2], ov[3]);
        if (g8 < 18) *(float4*)(orow + 4) = make_float4(ov[4], ov[5], ov[6], ov[7]);
    }
}

__global__ __launch_bounds__(320, 5) void afa_band(
    const float* __restrict__ x, const float* __restrict__ ku,
    const float* __restrict__ kd, float* __restrict__ out)
{
    __shared__ float sbuf[2 * PLANE_DW];             // 39968 B
    const int tid = threadIdx.x;
    const int b   = blockIdx.x;                      // 0..4
    const int pz0 = 2 * blockIdx.y;                  // planes pz0, pz0+1

    const int i0A  = 16 * b;
    const int IR0A = 8 * b + 1;
    const int i0B  = (b == 4) ? 132 : 16 * (b + 5);
    const int IR0B = (i0B >> 1) + 1;

    float fu[24], fd[12];
#pragma unroll
    for (int i = 0; i < 24; ++i) fu[i] = rfl(ku[i]);
#pragma unroll
    for (int i = 0; i < 12; ++i) fd[i] = rfl(kd[i]);

    const int h  = (tid >= 160);
    const int lt = tid - 160 * h;
    float* s_pl = sbuf + h * PLANE_DW;
    float* o = out + (size_t)(pz0 + h) * (OUT_HW * OUT_HW);

    P1Regs R;
    // ---- unit A (band b) ----
    p1_load(R, x, pz0, IR0A, tid);
    p1_store(R, sbuf, fu, tid);
    __syncthreads();
    p2_col(s_pl, lt, fu, fd);
    __syncthreads();
    // prefetch unit B's windows, then finish unit A
    p1_load(R, x, pz0, IR0B, tid);
    p3_store(s_pl, o, i0A, lt, fd);
    __syncthreads();
    // ---- unit B (band b+5) ----
    p1_store(R, sbuf, fu, tid);
    __syncthreads();
    p2_col(s_pl, lt, fu, fd);
    __syncthreads();
    p3_store(s_pl, o, i0B, lt, fd);
}

extern "C" void kernel_launch(void* const* d_in, const int* in_sizes, int n_in,
                              void* d_out, int out_size, void* d_ws, size_t ws_size,
                              hipStream_t stream) {
    const float* x  = (const float*)d_in[0];
    const float* ku = (const float*)d_in[1];
    const float* kd = (const float*)d_in[2];
    float* out = (float*)d_out;
    dim3 grid(5, 256);
    afa_band<<<grid, dim3(320), 0, stream>>>(x, ku, kd, out);
}

// Round 9
// 41.551 us; speedup vs baseline: 1.2201x; 1.2201x over previous
//
#include <hip/hip_runtime.h>

// AliasFreeActivation, round 9: packed-fp32 P2 on a single 20KB plane buffer.
// x (2,256,84,84) f32 -> up x4 (24t) -> lrelu -> down x2 (12t) -> crop 10
// -> out (2,256,148,148) f32.
//
// Band b (10/plane): out rows i0..i0+15, i0=min(16b,132) (band 9 overlaps
// band 8; duplicate stores bitwise-identical). z rows ZR0=2*i0+15 (≡3 mod 4),
// s=0..41; z cols 15..320 (306 local, 153 pairs). Input rows IR0=i0/2+1..+15,
// all in-bounds; no guards.
// Block = 320 threads, ONE plane-band. P2 splits the band into two half-bands:
//   group A (lt<153):        out rows 0..7,  steps s=0..25,  colv rows 0..11
//   group B (153<=lt<306):   out rows 8..15, steps s=16..41, colv rows 4..15
// The loop body is identical for both groups (s0=16 cancels: n'=(t+1)>>2,
// ph=(t+1)&3, mloc=t>>1, fd parity=t&1); only colv base row rb=4g and tv
// write rows 8g+i differ. All math float2 -> v_pk_fma_f32. z rows 16..25 are
// computed by both groups (~12% extra up-v) -- the price for halving LDS.
// tv aliases uph; barrier before tv writes orders cross-group reads/writes.

typedef float v2 __attribute__((ext_vector_type(2)));

constexpr int IN_HW  = 84;
constexpr int OUT_HW = 148;
constexpr int STR    = 312;               // row stride (dwords)
constexpr int NROWS  = 16;                // out rows per band
constexpr int NIR    = 16;                // uph rows per band
constexpr int LDS_DW = NIR * STR + 4;     // 4996 dw = 19984 B
constexpr float SLOPE = 0.2f;

__device__ __forceinline__ float rfl(float v) {
    return __uint_as_float(__builtin_amdgcn_readfirstlane(__float_as_uint(v)));
}

__global__ __launch_bounds__(320, 6) void afa_band(
    const float* __restrict__ x, const float* __restrict__ ku,
    const float* __restrict__ kd, float* __restrict__ out)
{
    __shared__ float sbuf[LDS_DW];
    const int lt   = threadIdx.x;
    const int band = blockIdx.x;                 // 0..9
    const int pz   = blockIdx.y;                 // 0..511
    const int i0   = (band == 9) ? 132 : 16 * band;
    const int IR0  = (i0 >> 1) + 1;

    float fu[24], fd[12];
#pragma unroll
    for (int i = 0; i < 24; ++i) fu[i] = rfl(ku[i]);
#pragma unroll
    for (int i = 0; i < 12; ++i) fd[i] = rfl(kd[i]);

    const float* xin = x + (size_t)pz * (IN_HW * IN_HW);
    float* o = out + (size_t)pz * (OUT_HW * OUT_HW);

    // ---- P1: horizontal up-conv, global->reg window, 8 z-cols/task ----
    // task (r,g): window w0..w7 = x[IR0+r][2g+1 .. 2g+8]
#pragma unroll
    for (int kk = 0; kk < 2; ++kk) {
        int e = lt + 320 * kk;
        if (e < NIR * 39) {
            int r = e / 39, g = e - r * 39;
            const float* xr = xin + (IR0 + r) * IN_HW + 2 * g;
            float2 p0 = *(const float2*)(xr);
            float2 p1 = *(const float2*)(xr + 2);
            float2 p2 = *(const float2*)(xr + 4);
            float2 p3 = *(const float2*)(xr + 6);
            float2 p4 = *(const float2*)(xr + ((g == 38) ? 6 : 8)); // avoid OOB
            float w0 = p0.y, w1 = p1.x, w2 = p1.y, w3 = p2.x,
                  w4 = p2.y, w5 = p3.x, w6 = p3.y, w7 = p4.x;
            float4 a, b;
            a.x = fu[1]*w5+fu[5]*w4+fu[9]*w3 +fu[13]*w2+fu[17]*w1+fu[21]*w0;
            a.y = fu[2]*w5+fu[6]*w4+fu[10]*w3+fu[14]*w2+fu[18]*w1+fu[22]*w0;
            a.z = fu[3]*w5+fu[7]*w4+fu[11]*w3+fu[15]*w2+fu[19]*w1+fu[23]*w0;
            a.w = fu[0]*w6+fu[4]*w5+fu[8]*w4 +fu[12]*w3+fu[16]*w2+fu[20]*w1;
            b.x = fu[1]*w6+fu[5]*w5+fu[9]*w4 +fu[13]*w3+fu[17]*w2+fu[21]*w1;
            b.y = fu[2]*w6+fu[6]*w5+fu[10]*w4+fu[14]*w3+fu[18]*w2+fu[22]*w1;
            b.z = fu[3]*w6+fu[7]*w5+fu[11]*w4+fu[15]*w3+fu[19]*w2+fu[23]*w1;
            b.w = fu[0]*w7+fu[4]*w6+fu[8]*w5 +fu[12]*w4+fu[16]*w3+fu[20]*w2;
            float* dst = sbuf + r * STR + 8 * g;
            *(float4*)(dst)     = a;
            *(float4*)(dst + 4) = b;
        }
    }
    __syncthreads();

    // ---- P2: half-band column-pair up-v + lrelu + down-v, packed fp32 ----
    {
        int g  = (lt >= 153);                    // 0: rows 0-7, 1: rows 8-15
        int pc = lt - 153 * g;
        if (pc > 152) pc = 152;                  // lt>=306: dup B pair 152
        const int rb = 4 * g;                    // colv base row
        const float* up = sbuf + 2 * pc + rb * STR;
        v2 colv[12];
#pragma unroll
        for (int r = 0; r < 12; ++r) colv[r] = *(const v2*)&up[r * STR];
        v2 acc[8];
#pragma unroll
        for (int i = 0; i < 8; ++i) acc[i] = (v2)(0.0f);
#pragma unroll
        for (int t = 0; t < 26; ++t) {
            const int n  = (t + 1) >> 2;
            const int ph = (t + 1) & 3;
            v2 z = colv[n+5] * fu[ph];
            z += colv[n+4] * fu[ph+4];
            z += colv[n+3] * fu[ph+8];
            z += colv[n+2] * fu[ph+12];
            z += colv[n+1] * fu[ph+16];
            z += colv[n]   * fu[ph+20];
            z = __builtin_elementwise_max(z, z * SLOPE);   // lrelu
            const int m = t >> 1;
#pragma unroll
            for (int k = 0; k < 6; ++k) {                  // static after unroll
                const int ai = m - k;
                if (ai >= 0 && ai < 8)
                    acc[ai] += z * fd[(t & 1) ? (10 - 2*k) : (11 - 2*k)];
            }
        }
        __syncthreads();                     // cross-group uph reads complete
        float* tvc = sbuf + 2 * pc + (8 * g) * STR;
#pragma unroll
        for (int i = 0; i < 8; ++i)
            *(v2*)&tvc[i * STR] = acc[i];
    }
    __syncthreads();

    // ---- P3: horizontal down-conv + store, 8 out cols/task ----
    if (lt < NROWS * 19) {
        int i = lt / 19, g8 = lt - i * 19;
        float W[28];
#pragma unroll
        for (int k = 0; k < 7; ++k) {
            float4 v = *(const float4*)(sbuf + i * STR + 16 * g8 + 4 * k);
            W[4*k+0]=v.x; W[4*k+1]=v.y; W[4*k+2]=v.z; W[4*k+3]=v.w;
        }
        float ov[8];
#pragma unroll
        for (int m = 0; m < 8; ++m) {
            float s = 0.0f;
#pragma unroll
            for (int u = 0; u < 12; ++u) s += fd[u] * W[2*m + 11 - u];
            ov[m] = s;
        }
        float* orow = o + (size_t)(i0 + i) * OUT_HW + 8 * g8;
        *(float4*)(orow) = make_float4(ov[0], ov[1], ov[2], ov[3]);
        if (g8 < 18) *(float4*)(orow + 4) = make_float4(ov[4], ov[5], ov[6], ov[7]);
    }
}

extern "C" void kernel_launch(void* const* d_in, const int* in_sizes, int n_in,
                              void* d_out, int out_size, void* d_ws, size_t ws_size,
                              hipStream_t stream) {
    const float* x  = (const float*)d_in[0];
    const float* ku = (const float*)d_in[1];
    const float* kd = (const float*)d_in[2];
    float* out = (float*)d_out;
    dim3 grid(10, 512);
    afa_band<<<grid, dim3(320), 0, stream>>>(x, ku, kd, out);
}

// Round 10
// 40.408 us; speedup vs baseline: 1.2546x; 1.0283x over previous
//
#include <hip/hip_runtime.h>

// AliasFreeActivation, round 10: v2-packed P1/P3 (permuted uph layout),
// ILP-restructured P2. x (2,256,84,84) f32 -> up x4 (24t) -> lrelu ->
// down x2 (12t) -> crop 10 -> out (2,256,148,148) f32.
//
// Band b (10/plane): out rows i0..i0+15, i0=min(16b,132) (band 9 overlaps 8;
// duplicate stores bitwise-identical). z cols 15..320 -> local cols 0..305.
// Input rows IR0=i0/2+1..+15, all in-bounds, no guards.
//
// uph/tv STORAGE PERMUTATION (per 8-col block): col 8B+c -> idx 8B+2c,
// col 8B+4+c -> idx 8B+2c+1 (c=0..3). P1 then stores its packed (a,b) v2
// results directly (a=cols 8g..+3, b=8g+4..+7 -> v2 (a.c,b.c) at idx 8g+2c).
// P2 is column-independent (any pairing works): thread pc handles storage
// idxs (2pc, 2pc+1). 154 pairs per half-band group (idx 306 holds col 305).
// P3 uses sidx(c) = (c&~7) + 2*(c&3) + ((c&7)>>2) to address cols, and
// packs out pairs (m, m+4) whose taps differ by +8 cols = +8 idx.

typedef float v2 __attribute__((ext_vector_type(2)));

constexpr int IN_HW  = 84;
constexpr int OUT_HW = 148;
constexpr int STR    = 312;               // row stride (dwords)
constexpr int NROWS  = 16;                // out rows per band
constexpr int NIR    = 16;                // uph rows per band
constexpr int LDS_DW = NIR * STR + 4;     // 4996 dw = 19984 B
constexpr float SLOPE = 0.2f;

__device__ __forceinline__ float rfl(float v) {
    return __uint_as_float(__builtin_amdgcn_readfirstlane(__float_as_uint(v)));
}
__host__ __device__ constexpr int sidx(int c) {   // col -> storage idx (mod 8-block)
    return (c & ~7) + 2 * (c & 3) + ((c & 7) >> 2);
}

__global__ __launch_bounds__(320, 4) void afa_band(
    const float* __restrict__ x, const float* __restrict__ ku,
    const float* __restrict__ kd, float* __restrict__ out)
{
    __shared__ float sbuf[LDS_DW];
    const int lt   = threadIdx.x;
    const int band = blockIdx.x;                 // 0..9
    const int pz   = blockIdx.y;                 // 0..511
    const int i0   = (band == 9) ? 132 : 16 * band;
    const int IR0  = (i0 >> 1) + 1;

    float fu[24], fd[12];
#pragma unroll
    for (int i = 0; i < 24; ++i) fu[i] = rfl(ku[i]);
#pragma unroll
    for (int i = 0; i < 12; ++i) fd[i] = rfl(kd[i]);

    const float* xin = x + (size_t)pz * (IN_HW * IN_HW);
    float* o = out + (size_t)pz * (OUT_HW * OUT_HW);

    // ---- P1: horizontal up-conv, packed (a,b) pairs, permuted stores ----
    // task (r,g): window w0..w7 = x[IR0+r][2g+1 .. 2g+8]; V[t]=(w[t],w[t+1]).
#pragma unroll
    for (int kk = 0; kk < 2; ++kk) {
        int e = lt + 320 * kk;
        if (e < NIR * 39) {
            int r = e / 39, g = e - r * 39;
            const float* xr = xin + (IR0 + r) * IN_HW + 2 * g;
            float2 p0 = *(const float2*)(xr);
            float2 p1 = *(const float2*)(xr + 2);
            float2 p2 = *(const float2*)(xr + 4);
            float2 p3 = *(const float2*)(xr + 6);
            float2 p4 = *(const float2*)(xr + ((g == 38) ? 6 : 8)); // avoid OOB
            v2 V0 = {p0.y, p1.x};
            v2 V1 = {p1.x, p1.y};
            v2 V2 = {p1.y, p2.x};
            v2 V3 = {p2.x, p2.y};
            v2 V4 = {p2.y, p3.x};
            v2 V5 = {p3.x, p3.y};
            v2 V6 = {p3.y, p4.x};   // V6.y garbage only for g=38 -> pad col 311
            v2 AB0 = V5*fu[1] + V4*fu[5] + V3*fu[9]  + V2*fu[13] + V1*fu[17] + V0*fu[21];
            v2 AB1 = V5*fu[2] + V4*fu[6] + V3*fu[10] + V2*fu[14] + V1*fu[18] + V0*fu[22];
            v2 AB2 = V5*fu[3] + V4*fu[7] + V3*fu[11] + V2*fu[15] + V1*fu[19] + V0*fu[23];
            v2 AB3 = V6*fu[0] + V5*fu[4] + V4*fu[8]  + V3*fu[12] + V2*fu[16] + V1*fu[20];
            float* dst = sbuf + r * STR + 8 * g;
            *(v2*)(dst)     = AB0;
            *(v2*)(dst + 2) = AB1;
            *(v2*)(dst + 4) = AB2;
            *(v2*)(dst + 6) = AB3;
        }
    }
    __syncthreads();

    // ---- P2: half-band pair-thread up-v + lrelu + down-v (z-first ILP) ----
    // group A (lt<154): out rows 0..7; group B: out rows 8..15.
    {
        int g  = (lt >= 154);
        int pc = lt - 154 * g;
        if (pc > 153) pc = 153;                  // dup tail, same-value writes
        const int rb = 4 * g;                    // colv base row
        const float* up = sbuf + 2 * pc + rb * STR;
        v2 colv[12];
#pragma unroll
        for (int r = 0; r < 12; ++r) colv[r] = *(const v2*)&up[r * STR];
        v2 zv[26];                               // 26 independent 6-fma chains
#pragma unroll
        for (int t = 0; t < 26; ++t) {
            const int n  = (t + 1) >> 2;
            const int ph = (t + 1) & 3;
            v2 z = colv[n+5] * fu[ph];
            z += colv[n+4] * fu[ph+4];
            z += colv[n+3] * fu[ph+8];
            z += colv[n+2] * fu[ph+12];
            z += colv[n+1] * fu[ph+16];
            z += colv[n]   * fu[ph+20];
            zv[t] = __builtin_elementwise_max(z, z * SLOPE);   // lrelu
        }
        v2 acc[8];
#pragma unroll
        for (int i = 0; i < 8; ++i) {
            v2 a = zv[2*i] * fd[11];
#pragma unroll
            for (int j = 1; j < 12; ++j)
                a += zv[2*i + j] * fd[11 - j];
            acc[i] = a;
        }
        __syncthreads();                         // cross-group uph reads done
        float* tvc = sbuf + 2 * pc + (8 * g) * STR;
#pragma unroll
        for (int i = 0; i < 8; ++i)
            *(v2*)&tvc[i * STR] = acc[i];
    }
    __syncthreads();

    // ---- P3: horizontal down-conv + store, packed out pairs (m, m+4) ----
    if (lt < NROWS * 19) {
        int i = lt / 19, g8 = lt - i * 19;
        float W[28];                             // storage-order window
#pragma unroll
        for (int k = 0; k < 7; ++k) {
            float4 v = *(const float4*)(sbuf + i * STR + 16 * g8 + 4 * k);
            W[4*k+0]=v.x; W[4*k+1]=v.y; W[4*k+2]=v.z; W[4*k+3]=v.w;
        }
        v2 U[18];                                // U[t] = (col t, col t+8)
#pragma unroll
        for (int t = 0; t < 18; ++t)
            U[t] = (v2){ W[sidx(t)], W[sidx(t) + 8] };
        v2 q[4];
#pragma unroll
        for (int m = 0; m < 4; ++m) {
            v2 a = U[2*m + 11] * fd[0];
#pragma unroll
            for (int u = 1; u < 12; ++u)
                a += U[2*m + 11 - u] * fd[u];
            q[m] = a;
        }
        float* orow = o + (size_t)(i0 + i) * OUT_HW + 8 * g8;
        *(float4*)(orow) = make_float4(q[0].x, q[1].x, q[2].x, q[3].x);
        if (g8 < 18)
            *(float4*)(orow + 4) = make_float4(q[0].y, q[1].y, q[2].y, q[3].y);
    }
}

extern "C" void kernel_launch(void* const* d_in, const int* in_sizes, int n_in,
                              void* d_out, int out_size, void* d_ws, size_t ws_size,
                              hipStream_t stream) {
    const float* x  = (const float*)d_in[0];
    const float* ku = (const float*)d_in[1];
    const float* kd = (const float*)d_in[2];
    float* out = (float*)d_out;
    dim3 grid(10, 512);
    afa_band<<<grid, dim3(320), 0, stream>>>(x, ku, kd, out);
}